// Round 7
// baseline (37.054 us; speedup 1.0000x reference)
//
#include <hip/hip_runtime.h>

// Bessel order-5 IIR -> truncated FIR (K=20; max pole |p|~0.64 -> tail ~1.3e-4,
// error ~2e-3 vs threshold 7.5e-2). Linearity: xmax*lfilter(x/xmax)==lfilter(x).
//
// Single fused kernel, blocked layout (R5 proved lane-stride layout triples TCC
// write traffic; R2/R6 blocked form measured WRITE=65MB). Per-thread: 13 fx4
// clustered window loads -> sched_barrier -> (thread 0: 20-step IIR impulse
// response into LDS) -> barrier -> 20x32 FMA -> 8 fx4 stores.

#define K_TAPS 20
#define OPT 32                        // outputs per thread
#define BLOCK 256
#define OPB (BLOCK * OPT)             // 8192 outputs per block
#define T_LEN 1048576
#define BATCH 16
#define TILES_PER_ROW (T_LEN / OPB)   // 128
#define NW (OPT + K_TAPS)             // 52-float window
#define NV (NW / 4)                   // 13 float4 loads

typedef float fx4 __attribute__((ext_vector_type(4)));

__global__ __launch_bounds__(BLOCK, 4) void bessel_fused(
    const float* __restrict__ x, const float* __restrict__ bcoef,
    const float* __restrict__ acoef, float* __restrict__ y) {
    const int bid  = blockIdx.x;
    const int row  = bid >> 7;                    // TILES_PER_ROW = 128
    const int tile = bid & (TILES_PER_ROW - 1);
    const int G    = tile * OPB + (int)threadIdx.x * OPT;
    const float* __restrict__ xr = x + (size_t)row * T_LEN;
    float* __restrict__ yr       = y + (size_t)row * T_LEN;

    __shared__ float hsh[K_TAPS];

    // ---- phase 1: issue the whole window load burst (w[i] = x[G-20+i]) ----
    fx4 v[NV];
    if (G >= K_TAPS) {
        const fx4* src = (const fx4*)(xr + (G - K_TAPS));  // 16B-aligned (G%32==0)
#pragma unroll
        for (int i = 0; i < NV; ++i) v[i] = src[i];
    } else {
        // G==0 only (1 thread per row): zero initial state == zero padding
        float tmp[NW];
#pragma unroll
        for (int i = 0; i < NW; ++i) {
            int gi = G - K_TAPS + i;
            tmp[i] = (gi >= 0) ? xr[gi] : 0.0f;
        }
#pragma unroll
        for (int i = 0; i < NV; ++i)
            v[i] = (fx4){tmp[4*i], tmp[4*i+1], tmp[4*i+2], tmp[4*i+3]};
    }
    __builtin_amdgcn_sched_barrier(0);   // keep the burst clustered

    // ---- phase 2: thread 0 computes the impulse response into LDS ----
    if (threadIdx.x == 0) {
        float bb[6], aa[6];
        float inv = 1.0f / acoef[0];
#pragma unroll
        for (int i = 0; i < 6; ++i) { bb[i] = bcoef[i] * inv; aa[i] = acoef[i] * inv; }
        float z0 = 0.f, z1 = 0.f, z2 = 0.f, z3 = 0.f, z4 = 0.f;
#pragma unroll
        for (int t = 0; t < K_TAPS; ++t) {
            float xt = (t == 0) ? 1.0f : 0.0f;
            float yv = fmaf(bb[0], xt, z0);
            z0 = fmaf(bb[1], xt, z1) - aa[1] * yv;
            z1 = fmaf(bb[2], xt, z2) - aa[2] * yv;
            z2 = fmaf(bb[3], xt, z3) - aa[3] * yv;
            z3 = fmaf(bb[4], xt, z4) - aa[4] * yv;
            z4 = bb[5] * xt - aa[5] * yv;
            hsh[t] = yv;
        }
    }
    __syncthreads();                     // overlaps the in-flight loads

    float hs[K_TAPS];
#pragma unroll
    for (int k = 0; k < K_TAPS; ++k) hs[k] = hsh[k];   // LDS broadcast reads

    // ---- phase 3: FIR, window indexed straight out of v[] (compile-time) ----
    float acc[OPT];
#pragma unroll
    for (int j = 0; j < OPT; ++j) acc[j] = 0.0f;
#pragma unroll
    for (int k = 0; k < K_TAPS; ++k) {
#pragma unroll
        for (int j = 0; j < OPT; ++j) {
            const int i = K_TAPS + j - k;            // 0..51, compile-time
            acc[j] = fmaf(hs[k], v[i >> 2][i & 3], acc[j]);
        }
    }

    // ---- phase 4: plain cached stores (nt proven 3x write amplification) ----
    fx4* oy = (fx4*)(yr + G);
#pragma unroll
    for (int q = 0; q < OPT / 4; ++q) {
        fx4 o = {acc[4*q], acc[4*q+1], acc[4*q+2], acc[4*q+3]};
        oy[q] = o;
    }
}

extern "C" void kernel_launch(void* const* d_in, const int* in_sizes, int n_in,
                              void* d_out, int out_size, void* d_ws, size_t ws_size,
                              hipStream_t stream) {
    const float* x = (const float*)d_in[0];
    const float* b = (const float*)d_in[1];
    const float* a = (const float*)d_in[2];
    float* y = (float*)d_out;

    hipLaunchKernelGGL(bessel_fused, dim3(BATCH * TILES_PER_ROW), dim3(BLOCK), 0,
                       stream, x, b, a, y);
}

// Round 9
// 34.460 us; speedup vs baseline: 1.0753x; 1.0753x over previous
//
#include <hip/hip_runtime.h>

// Bessel order-5 IIR -> truncated FIR (K=20; max pole |p|~0.64 -> tail ~1.3e-4,
// output error ~2e-3 vs threshold 7.5e-2). Linearity: xmax*lfilter(x/xmax)==
// lfilter(x) -> skip normalization entirely.
//
// R6 skeleton (proven 33.1us): blocked layout OPT=16, clustered burst,
// launch_bounds(256,4), plain cached stores (nt = 3x write amplification, R4;
// lane-stride layout = 3.5x TCC writes, R5). Grafts: K=20, h computed once by
// thread 0 into LDS (serial IIR hides under load latency), taps pinned to
// SGPRs via readfirstlane — BITCAST through int (R8 bug: float arg to the
// int builtin value-converted every tap to 0).

#define K_TAPS 20
#define OPT 16                        // outputs per thread (R7: 32 regressed)
#define BLOCK 256
#define OPB (BLOCK * OPT)             // 4096 outputs per block
#define T_LEN 1048576
#define BATCH 16
#define TILES_PER_ROW (T_LEN / OPB)   // 256
#define NW (OPT + K_TAPS)             // 36-float window
#define NV (NW / 4)                   // 9 float4 loads

typedef float fx4 __attribute__((ext_vector_type(4)));

__global__ __launch_bounds__(BLOCK, 4) void bessel_fused(
    const float* __restrict__ x, const float* __restrict__ bcoef,
    const float* __restrict__ acoef, float* __restrict__ y) {
    const int bid  = blockIdx.x;
    const int row  = bid >> 8;                    // TILES_PER_ROW = 256
    const int tile = bid & (TILES_PER_ROW - 1);
    const int G    = tile * OPB + (int)threadIdx.x * OPT;
    const float* __restrict__ xr = x + (size_t)row * T_LEN;
    float* __restrict__ yr       = y + (size_t)row * T_LEN;

    __shared__ float hsh[K_TAPS];

    // ---- phase 1: issue the whole window load burst (w[i] = x[G-20+i]) ----
    fx4 v[NV];
    if (G >= K_TAPS) {
        const fx4* src = (const fx4*)(xr + (G - K_TAPS));  // 16B-aligned (G%16==0)
#pragma unroll
        for (int i = 0; i < NV; ++i) v[i] = src[i];
    } else {
        // G==0 only (1 thread per row): zero initial state == zero padding
        float tmp[NW];
#pragma unroll
        for (int i = 0; i < NW; ++i) {
            int gi = G - K_TAPS + i;
            tmp[i] = (gi >= 0) ? xr[gi] : 0.0f;
        }
#pragma unroll
        for (int i = 0; i < NV; ++i)
            v[i] = (fx4){tmp[4*i], tmp[4*i+1], tmp[4*i+2], tmp[4*i+3]};
    }
    __builtin_amdgcn_sched_barrier(0);   // keep the burst clustered

    // ---- phase 2: thread 0 computes impulse response into LDS; the serial
    // dependent chain (~800cy) overlaps the in-flight global loads ----
    if (threadIdx.x == 0) {
        float bb[6], aa[6];
        float inv = 1.0f / acoef[0];
#pragma unroll
        for (int i = 0; i < 6; ++i) { bb[i] = bcoef[i] * inv; aa[i] = acoef[i] * inv; }
        float z0 = 0.f, z1 = 0.f, z2 = 0.f, z3 = 0.f, z4 = 0.f;
#pragma unroll
        for (int t = 0; t < K_TAPS; ++t) {
            float xt = (t == 0) ? 1.0f : 0.0f;
            float yv = fmaf(bb[0], xt, z0);
            z0 = fmaf(bb[1], xt, z1) - aa[1] * yv;
            z1 = fmaf(bb[2], xt, z2) - aa[2] * yv;
            z2 = fmaf(bb[3], xt, z3) - aa[3] * yv;
            z3 = fmaf(bb[4], xt, z4) - aa[4] * yv;
            z4 = bb[5] * xt - aa[5] * yv;
            hsh[t] = yv;
        }
    }
    __syncthreads();

    // taps -> SGPRs (wave-uniform). NOTE: readfirstlane is an int builtin —
    // must BITCAST, not value-convert (R8 failure mode).
    float hs[K_TAPS];
#pragma unroll
    for (int k = 0; k < K_TAPS; ++k)
        hs[k] = __int_as_float(__builtin_amdgcn_readfirstlane(__float_as_int(hsh[k])));

    // ---- phase 3: FIR, window indexed straight out of v[] (compile-time) ----
    float acc[OPT];
#pragma unroll
    for (int j = 0; j < OPT; ++j) acc[j] = 0.0f;
#pragma unroll
    for (int k = 0; k < K_TAPS; ++k) {
#pragma unroll
        for (int j = 0; j < OPT; ++j) {
            const int i = K_TAPS + j - k;            // 0..35, compile-time
            acc[j] = fmaf(hs[k], v[i >> 2][i & 3], acc[j]);
        }
    }

    // ---- phase 4: plain cached stores ----
    fx4* oy = (fx4*)(yr + G);
#pragma unroll
    for (int q = 0; q < OPT / 4; ++q) {
        fx4 o = {acc[4*q], acc[4*q+1], acc[4*q+2], acc[4*q+3]};
        oy[q] = o;
    }
}

extern "C" void kernel_launch(void* const* d_in, const int* in_sizes, int n_in,
                              void* d_out, int out_size, void* d_ws, size_t ws_size,
                              hipStream_t stream) {
    const float* x = (const float*)d_in[0];
    const float* b = (const float*)d_in[1];
    const float* a = (const float*)d_in[2];
    float* y = (float*)d_out;

    hipLaunchKernelGGL(bessel_fused, dim3(BATCH * TILES_PER_ROW), dim3(BLOCK), 0,
                       stream, x, b, a, y);
}

// Round 10
// 25.783 us; speedup vs baseline: 1.4371x; 1.3365x over previous
//
#include <hip/hip_runtime.h>

// Bessel order-5 IIR -> truncated FIR (K=20; max pole |p|~0.64 -> tail ~1.3e-4,
// output error ~2e-3 vs threshold 7.5e-2). Linearity: xmax*lfilter(x/xmax)==
// lfilter(x) -> skip normalization entirely.
//
// R10: occupancy push. OPT=8 -> window 7xfx4 + 8 acc ~ 48 VGPR, fits the
// 64-VGPR cap of launch_bounds(256,8) -> up to 32 waves/CU (was capped at 16).
// Keeps: blocked layout (R5: lane-stride = 3.5x TCC writes), clustered burst +
// sched_barrier (R4/R6), plain cached stores (R4: nt = 3x write amp), fused
// thread0 IIR -> LDS -> SGPR taps via bitcast readfirstlane (R8 bug fixed).

#define K_TAPS 20
#define OPT 8                         // outputs per thread
#define BLOCK 256
#define OPB (BLOCK * OPT)             // 2048 outputs per block
#define T_LEN 1048576
#define BATCH 16
#define TILES_PER_ROW (T_LEN / OPB)   // 512
#define NW (OPT + K_TAPS)             // 28-float window
#define NV (NW / 4)                   // 7 float4 loads

typedef float fx4 __attribute__((ext_vector_type(4)));

__global__ __launch_bounds__(BLOCK, 8) void bessel_fused(
    const float* __restrict__ x, const float* __restrict__ bcoef,
    const float* __restrict__ acoef, float* __restrict__ y) {
    const int bid  = blockIdx.x;
    const int row  = bid >> 9;                    // TILES_PER_ROW = 512
    const int tile = bid & (TILES_PER_ROW - 1);
    const int G    = tile * OPB + (int)threadIdx.x * OPT;
    const float* __restrict__ xr = x + (size_t)row * T_LEN;
    float* __restrict__ yr       = y + (size_t)row * T_LEN;

    __shared__ float hsh[K_TAPS];

    // ---- phase 1: issue the whole window load burst (w[i] = x[G-20+i]) ----
    fx4 v[NV];
    if (G >= K_TAPS) {
        const fx4* src = (const fx4*)(xr + (G - K_TAPS));  // (G-20)%4==0 -> 16B aligned
#pragma unroll
        for (int i = 0; i < NV; ++i) v[i] = src[i];
    } else {
        // G==0 only (1 thread per row): zero initial state == zero padding
        float tmp[NW];
#pragma unroll
        for (int i = 0; i < NW; ++i) {
            int gi = G - K_TAPS + i;
            tmp[i] = (gi >= 0) ? xr[gi] : 0.0f;
        }
#pragma unroll
        for (int i = 0; i < NV; ++i)
            v[i] = (fx4){tmp[4*i], tmp[4*i+1], tmp[4*i+2], tmp[4*i+3]};
    }
    __builtin_amdgcn_sched_barrier(0);   // keep the burst clustered

    // ---- phase 2: thread 0 computes impulse response into LDS; serial chain
    // overlaps the in-flight global loads ----
    if (threadIdx.x == 0) {
        float bb[6], aa[6];
        float inv = 1.0f / acoef[0];
#pragma unroll
        for (int i = 0; i < 6; ++i) { bb[i] = bcoef[i] * inv; aa[i] = acoef[i] * inv; }
        float z0 = 0.f, z1 = 0.f, z2 = 0.f, z3 = 0.f, z4 = 0.f;
#pragma unroll
        for (int t = 0; t < K_TAPS; ++t) {
            float xt = (t == 0) ? 1.0f : 0.0f;
            float yv = fmaf(bb[0], xt, z0);
            z0 = fmaf(bb[1], xt, z1) - aa[1] * yv;
            z1 = fmaf(bb[2], xt, z2) - aa[2] * yv;
            z2 = fmaf(bb[3], xt, z3) - aa[3] * yv;
            z3 = fmaf(bb[4], xt, z4) - aa[4] * yv;
            z4 = bb[5] * xt - aa[5] * yv;
            hsh[t] = yv;
        }
    }
    __syncthreads();

    // taps -> SGPRs (wave-uniform); BITCAST, not value-convert (R8 bug)
    float hs[K_TAPS];
#pragma unroll
    for (int k = 0; k < K_TAPS; ++k)
        hs[k] = __int_as_float(__builtin_amdgcn_readfirstlane(__float_as_int(hsh[k])));

    // ---- phase 3: FIR, window indexed straight out of v[] (compile-time) ----
    float acc[OPT];
#pragma unroll
    for (int j = 0; j < OPT; ++j) acc[j] = 0.0f;
#pragma unroll
    for (int k = 0; k < K_TAPS; ++k) {
#pragma unroll
        for (int j = 0; j < OPT; ++j) {
            const int i = K_TAPS + j - k;            // 0..27, compile-time
            acc[j] = fmaf(hs[k], v[i >> 2][i & 3], acc[j]);
        }
    }

    // ---- phase 4: plain cached stores ----
    fx4* oy = (fx4*)(yr + G);
#pragma unroll
    for (int q = 0; q < OPT / 4; ++q) {
        fx4 o = {acc[4*q], acc[4*q+1], acc[4*q+2], acc[4*q+3]};
        oy[q] = o;
    }
}

extern "C" void kernel_launch(void* const* d_in, const int* in_sizes, int n_in,
                              void* d_out, int out_size, void* d_ws, size_t ws_size,
                              hipStream_t stream) {
    const float* x = (const float*)d_in[0];
    const float* b = (const float*)d_in[1];
    const float* a = (const float*)d_in[2];
    float* y = (float*)d_out;

    hipLaunchKernelGGL(bessel_fused, dim3(BATCH * TILES_PER_ROW), dim3(BLOCK), 0,
                       stream, x, b, a, y);
}